// Round 2
// baseline (466.346 us; speedup 1.0000x reference)
//
#include <hip/hip_runtime.h>

#define NWG     16
#define NTHR    512
#define HIDDEN  256
#define HPW     16     // h indices per WG
#define ENC_T   16
#define NTOK    28
#define DECLEN  25

__device__ __forceinline__ float sigf(float x){ return 1.0f/(1.0f + expf(-x)); }
__device__ __forceinline__ float4 ld4(const float* p){ return *(const float4*)p; }

__device__ __forceinline__ void gstoref(float* p, float v){
  __hip_atomic_store(p, v, __ATOMIC_RELAXED, __HIP_MEMORY_SCOPE_AGENT);
}
__device__ __forceinline__ float gloadf(const float* p){
  return __hip_atomic_load(p, __ATOMIC_RELAXED, __HIP_MEMORY_SCOPE_AGENT);
}

__global__ __launch_bounds__(NTHR, 1) void vae_lstm_kernel(
    const int* __restrict__ data, const int* __restrict__ data_c, const int* __restrict__ target_c,
    const float* __restrict__ cond_emb, const float* __restrict__ enc_emb,
    const float* __restrict__ eWih, const float* __restrict__ eWhh,
    const float* __restrict__ ebih, const float* __restrict__ ebhh,
    const float* __restrict__ hmuW, const float* __restrict__ hmub,
    const float* __restrict__ cmuW, const float* __restrict__ cmub,
    const float* __restrict__ fc1W, const float* __restrict__ fc1b,
    const float* __restrict__ fc2W, const float* __restrict__ fc2b,
    const float* __restrict__ dec_emb, const float* __restrict__ dWih,
    const float* __restrict__ dWhh, const float* __restrict__ dbih, const float* __restrict__ dbhh,
    const float* __restrict__ outW, const float* __restrict__ outb,
    float* __restrict__ out,
    int* __restrict__ flags, float* __restrict__ hbuf, float* __restrict__ cbuf)
{
  __shared__ __align__(16) float h_sh[HIDDEN];
  __shared__ __align__(16) float c2_sh[HIDDEN];
  __shared__ float pxe_sh[ENC_T][64];
  __shared__ float pxd_sh[NTOK][64];
  __shared__ float g_sh[64];
  __shared__ float mu_sh[64];
  __shared__ float l_sh[NTOK];
  __shared__ float c_sh[HPW];
  __shared__ float tc_sh[8];
  __shared__ float outb_sh[NTOK];
  __shared__ int tok_sh;

  const int w   = blockIdx.x;
  const int tid = threadIdx.x;
  const int r   = tid >> 3;        // 0..63 : gate*16 + j
  const int p   = tid & 7;         // column part (32 cols each)
  const int gate = r >> 4;         // 0..3 (i,f,g,o)
  const int j    = r & 15;         // h index within WG
  const int grow = gate*HIDDEN + w*HPW + j;   // global gate row 0..1023

  // ---------------- prologue: weights -> registers ----------------
  float4 wenc[8], wdec[8], wout[8];
  #pragma unroll
  for (int k=0;k<8;++k){
    const int c = (p*8+k)*4;
    wenc[k] = ld4(eWhh + (size_t)grow*HIDDEN + c);
    wdec[k] = ld4(dWhh + (size_t)grow*HIDDEN + c);
  }
  if (r < NTOK){
    #pragma unroll
    for (int k=0;k<8;++k) wout[k] = ld4(outW + (size_t)r*HIDDEN + (p*8+k)*4);
  } else {
    #pragma unroll
    for (int k=0;k<8;++k) wout[k] = make_float4(0.f,0.f,0.f,0.f);
  }

  // px for encoder steps: x_t @ Wih.T + bih + bhh  (own 64 rows, all 16 steps)
  {
    const float bsum = ebih[grow] + ebhh[grow];
    for (int ss = p; ss < ENC_T; ss += 8){
      const float* x  = enc_emb + (size_t)data[ss]*HIDDEN;
      const float* Wr = eWih + (size_t)grow*HIDDEN;
      float a = bsum;
      for (int c4=0;c4<64;++c4){
        float4 wv = ld4(Wr + c4*4); float4 xv = ld4(x + c4*4);
        a = fmaf(wv.x,xv.x, fmaf(wv.y,xv.y, fmaf(wv.z,xv.z, fmaf(wv.w,xv.w, a))));
      }
      pxe_sh[ss][r] = a;
    }
  }
  // px for ALL 28 possible decoder tokens: relu(dec_emb[tok]) @ Wih.T + biases
  {
    const float bsum = dbih[grow] + dbhh[grow];
    for (int tk = p; tk < NTOK; tk += 8){
      const float* x  = dec_emb + (size_t)tk*HIDDEN;
      const float* Wr = dWih + (size_t)grow*HIDDEN;
      float a = bsum;
      for (int c4=0;c4<64;++c4){
        float4 wv = ld4(Wr + c4*4); float4 xv = ld4(x + c4*4);
        a = fmaf(wv.x,fmaxf(xv.x,0.f), fmaf(wv.y,fmaxf(xv.y,0.f),
            fmaf(wv.z,fmaxf(xv.z,0.f), fmaf(wv.w,fmaxf(xv.w,0.f), a))));
      }
      pxd_sh[tk][r] = a;
    }
  }

  const int dcnd = data_c[0];
  if (tid < 8)    tc_sh[tid]   = cond_emb[target_c[0]*8 + tid];
  if (tid < NTOK) outb_sh[tid] = outb[tid];
  if (tid < HIDDEN)
    h_sh[tid] = (tid >= HIDDEN-8) ? cond_emb[dcnd*8 + (tid-(HIDDEN-8))] : 0.f;
  if (tid < HPW){
    int idx = w*HPW + tid;
    c_sh[tid] = (idx >= HIDDEN-8) ? cond_emb[dcnd*8 + (idx-(HIDDEN-8))] : 0.f;
  }
  __syncthreads();

  // h segment (32 cols, p*32 .. p*32+31) lives in registers
  float4 hreg[8];
  #pragma unroll
  for (int k=0;k<8;++k) hreg[k] = ld4(h_sh + p*32 + k*4);
  __syncthreads();

  int step = 1;
  // ---------------- encoder: 16 sequential steps ----------------
  for (int es=0; es<ENC_T; ++es, ++step){
    float a = 0.f;
    #pragma unroll
    for (int k=0;k<8;++k){
      float4 hv = hreg[k]; float4 wv = wenc[k];
      a = fmaf(wv.x,hv.x, fmaf(wv.y,hv.y, fmaf(wv.z,hv.z, fmaf(wv.w,hv.w, a))));
    }
    a += __shfl_xor(a,1); a += __shfl_xor(a,2); a += __shfl_xor(a,4);
    if (p==0) g_sh[r] = a + pxe_sh[es][r];
    __syncthreads();
    if (tid < HPW){
      float gi=g_sh[tid], gf=g_sh[16+tid], gg=g_sh[32+tid], go=g_sh[48+tid];
      float cc = sigf(gf)*c_sh[tid] + sigf(gi)*tanhf(gg);
      float hh = sigf(go)*tanhf(cc);
      c_sh[tid]=cc;
      gstoref(&hbuf[(step&1)*HIDDEN + w*HPW + tid], hh);
      if (es==ENC_T-1) gstoref(&cbuf[w*HPW + tid], cc);
    }
    __syncthreads();   // drains producers' vmcnt before flag
    if (tid==0) __hip_atomic_store(&flags[w], step, __ATOMIC_RELEASE, __HIP_MEMORY_SCOPE_AGENT);
    if (tid < 64){     // wave 0 polls all 16 flags (one cacheline) with RELAXED loads
      for (;;){
        int v = __hip_atomic_load(&flags[tid & (NWG-1)], __ATOMIC_RELAXED, __HIP_MEMORY_SCOPE_AGENT);
        if (__all(v >= step)) break;
      }
    }
    __syncthreads();
    __builtin_amdgcn_fence(__ATOMIC_ACQUIRE, "agent");
    { // direct global -> register reload of own 32-col segment (no LDS hop)
      const float* hcur = hbuf + (step&1)*HIDDEN + p*32;
      #pragma unroll
      for (int k=0;k<8;++k){
        float4 t;
        t.x = gloadf(hcur + k*4 + 0); t.y = gloadf(hcur + k*4 + 1);
        t.z = gloadf(hcur + k*4 + 2); t.w = gloadf(hcur + k*4 + 3);
        hreg[k] = t;
      }
    }
  }

  // ---------------- mid: mu's + fc1/fc2 (redundant per WG, zero extra syncs) ----------------
  if (tid < HIDDEN){
    h_sh[tid]  = gloadf(&hbuf[(ENC_T&1)*HIDDEN + tid]);   // h_T (parity 0)
    c2_sh[tid] = gloadf(&cbuf[tid]);                      // c_T
  }
  __syncthreads();
  if (tid < 256){
    int row = tid>>2, q = tid&3;   // 64 rows (32 h_mu + 32 c_mu), 4 threads each
    const float* Wr = (row<32) ? (hmuW + (size_t)row*HIDDEN) : (cmuW + (size_t)(row-32)*HIDDEN);
    const float* v  = (row<32) ? h_sh : c2_sh;
    float a=0.f;
    for (int c4=q*16; c4<q*16+16; ++c4){
      float4 wv = ld4(Wr + c4*4);
      float4 vv = *(const float4*)(v + c4*4);
      a = fmaf(wv.x,vv.x, fmaf(wv.y,vv.y, fmaf(wv.z,vv.z, fmaf(wv.w,vv.w, a))));
    }
    a += __shfl_xor(a,1); a += __shfl_xor(a,2);
    if (q==0) mu_sh[row] = a + ((row<32)? hmub[row] : cmub[row-32]);
  }
  __syncthreads();
  {
    float a = 0.f;
    if (tid < 256){
      a = fc1b[tid];
      const float* Wr = fc1W + (size_t)tid*40;
      #pragma unroll
      for (int k=0;k<32;++k) a = fmaf(Wr[k], mu_sh[k], a);
      #pragma unroll
      for (int k=0;k<8;++k)  a = fmaf(Wr[32+k], tc_sh[k], a);
    }
    float a2 = 0.f;
    if (tid < HPW){
      int idx = w*HPW + tid;
      a2 = fc2b[idx];
      const float* W2 = fc2W + (size_t)idx*40;
      #pragma unroll
      for (int k=0;k<32;++k) a2 = fmaf(W2[k], mu_sh[32+k], a2);
      #pragma unroll
      for (int k=0;k<8;++k)  a2 = fmaf(W2[32+k], tc_sh[k], a2);
    }
    __syncthreads();
    if (tid < 256) h_sh[tid] = a;   // decoder h0 (full, redundant in every WG)
    if (tid < HPW) c_sh[tid] = a2;  // decoder c0 (own slice only)
    __syncthreads();
  }
  #pragma unroll
  for (int k=0;k<8;++k) hreg[k] = ld4(h_sh + p*32 + k*4);
  __syncthreads();

  // ---------------- decoder: 25 sequential steps ----------------
  int tok = 0; // SOS
  for (int dt=0; dt<DECLEN; ++dt, ++step){
    float a=0.f;
    #pragma unroll
    for (int k=0;k<8;++k){
      float4 hv = hreg[k]; float4 wv = wdec[k];
      a = fmaf(wv.x,hv.x, fmaf(wv.y,hv.y, fmaf(wv.z,hv.z, fmaf(wv.w,hv.w, a))));
    }
    a += __shfl_xor(a,1); a += __shfl_xor(a,2); a += __shfl_xor(a,4);
    if (p==0) g_sh[r] = a + pxd_sh[tok][r];
    __syncthreads();
    if (tid < HPW){
      float gi=g_sh[tid], gf=g_sh[16+tid], gg=g_sh[32+tid], go=g_sh[48+tid];
      float cc = sigf(gf)*c_sh[tid] + sigf(gi)*tanhf(gg);
      float hh = sigf(go)*tanhf(cc);
      c_sh[tid]=cc;
      gstoref(&hbuf[(step&1)*HIDDEN + w*HPW + tid], hh);
    }
    __syncthreads();
    if (tid==0) __hip_atomic_store(&flags[w], step, __ATOMIC_RELEASE, __HIP_MEMORY_SCOPE_AGENT);
    if (tid < 64){
      for (;;){
        int v = __hip_atomic_load(&flags[tid & (NWG-1)], __ATOMIC_RELAXED, __HIP_MEMORY_SCOPE_AGENT);
        if (__all(v >= step)) break;
      }
    }
    __syncthreads();
    __builtin_amdgcn_fence(__ATOMIC_ACQUIRE, "agent");
    {
      const float* hcur = hbuf + (step&1)*HIDDEN + p*32;
      #pragma unroll
      for (int k=0;k<8;++k){
        float4 t;
        t.x = gloadf(hcur + k*4 + 0); t.y = gloadf(hcur + k*4 + 1);
        t.z = gloadf(hcur + k*4 + 2); t.w = gloadf(hcur + k*4 + 3);
        hreg[k] = t;
      }
    }
    // logits from the fresh h registers (redundant in every WG)
    if (r < NTOK){
      float la=0.f;
      #pragma unroll
      for (int k=0;k<8;++k){
        float4 hv = hreg[k]; float4 wv = wout[k];
        la = fmaf(wv.x,hv.x, fmaf(wv.y,hv.y, fmaf(wv.z,hv.z, fmaf(wv.w,hv.w, la))));
      }
      la += __shfl_xor(la,1); la += __shfl_xor(la,2); la += __shfl_xor(la,4);
      if (p==0) l_sh[r] = la + outb_sh[r];
    }
    __syncthreads();
    if (tid==0){
      float best = l_sh[0]; int bi=0;
      #pragma unroll
      for (int i=1;i<NTOK;++i){ if (l_sh[i] > best){ best=l_sh[i]; bi=i; } }
      tok_sh = bi;
    }
    __syncthreads();
    tok = tok_sh;
    if (w==0){
      if (tid < NTOK) out[dt*NTOK + tid] = l_sh[tid];
      if (tid==0)     out[DECLEN*NTOK + dt] = (float)tok_sh;
    }
  }
}

extern "C" void kernel_launch(void* const* d_in, const int* in_sizes, int n_in,
                              void* d_out, int out_size, void* d_ws, size_t ws_size,
                              hipStream_t stream)
{
  int*   flags = (int*)d_ws;                       // 16 ints (one cacheline)
  float* hbuf  = (float*)((char*)d_ws + 256);      // double-buffered h: 2*256 floats
  float* cbuf  = hbuf + 2*HIDDEN;                  // cT: 256 floats
  hipMemsetAsync(d_ws, 0, 256, stream);            // zero flags (captured each replay)

  vae_lstm_kernel<<<NWG, NTHR, 0, stream>>>(
    (const int*)d_in[0], (const int*)d_in[1], (const int*)d_in[2],
    (const float*)d_in[3], (const float*)d_in[4],
    (const float*)d_in[5], (const float*)d_in[6], (const float*)d_in[7], (const float*)d_in[8],
    (const float*)d_in[9], (const float*)d_in[10], (const float*)d_in[11], (const float*)d_in[12],
    (const float*)d_in[13], (const float*)d_in[14], (const float*)d_in[15], (const float*)d_in[16],
    (const float*)d_in[17], (const float*)d_in[18], (const float*)d_in[19], (const float*)d_in[20],
    (const float*)d_in[21], (const float*)d_in[22], (const float*)d_in[23],
    (float*)d_out, flags, hbuf, cbuf);
}

// Round 4
// 241.691 us; speedup vs baseline: 1.9295x; 1.9295x over previous
//
#include <hip/hip_runtime.h>

#define NWG     32
#define NTHR    256
#define HIDDEN  256
#define HPW     8      // h indices per WG
#define ENC_T   16
#define NTOK    28
#define DECLEN  25

typedef unsigned long long u64;

__device__ __forceinline__ float sigf(float x){ return 1.0f/(1.0f + expf(-x)); }
__device__ __forceinline__ float4 ld4(const float* p){ return *(const float4*)p; }

__device__ __forceinline__ void astore(u64* p, u64 v){
  __hip_atomic_store(p, v, __ATOMIC_RELAXED, __HIP_MEMORY_SCOPE_AGENT);
}
__device__ __forceinline__ u64 aload(const u64* p){
  return __hip_atomic_load(p, __ATOMIC_RELAXED, __HIP_MEMORY_SCOPE_AGENT);
}

__global__ __launch_bounds__(NTHR, 1) void vae_lstm_kernel(
    const int* __restrict__ data, const int* __restrict__ data_c, const int* __restrict__ target_c,
    const float* __restrict__ cond_emb, const float* __restrict__ enc_emb,
    const float* __restrict__ eWih, const float* __restrict__ eWhh,
    const float* __restrict__ ebih, const float* __restrict__ ebhh,
    const float* __restrict__ hmuW, const float* __restrict__ hmub,
    const float* __restrict__ cmuW, const float* __restrict__ cmub,
    const float* __restrict__ fc1W, const float* __restrict__ fc1b,
    const float* __restrict__ fc2W, const float* __restrict__ fc2b,
    const float* __restrict__ dec_emb, const float* __restrict__ dWih,
    const float* __restrict__ dWhh, const float* __restrict__ dbih, const float* __restrict__ dbhh,
    const float* __restrict__ outW, const float* __restrict__ outb,
    float* __restrict__ out, u64* __restrict__ hb, u64* __restrict__ cb)
{
  __shared__ __align__(16) float h_sh[HIDDEN];
  __shared__ __align__(16) float c2_sh[HIDDEN];
  __shared__ float pxe_sh[ENC_T][32];
  __shared__ float pxd_sh[NTOK][32];
  __shared__ float g_sh[32];
  __shared__ float mu_sh[64];
  __shared__ float l_sh[NTOK];
  __shared__ float c_sh[HPW];
  __shared__ float tc_sh[8];
  __shared__ float outb_sh[NTOK];
  __shared__ int tok_sh;

  const int w   = blockIdx.x;
  const int tid = threadIdx.x;
  const int r   = tid >> 3;        // 0..31 : gate*8 + j
  const int p   = tid & 7;         // column part (32 cols each)
  const int gate = r >> 3;         // 0..3 (i,f,g,o)
  const int j    = r & 7;          // h index within WG
  const int grow = gate*HIDDEN + w*HPW + j;   // global gate row 0..1023

  // ---------------- prologue: weights -> registers (R1-identical) ----------------
  float4 wenc[8], wdec[8], wout[8];
  #pragma unroll
  for (int k=0;k<8;++k){
    const int c = (p*8+k)*4;
    wenc[k] = ld4(eWhh + (size_t)grow*HIDDEN + c);
    wdec[k] = ld4(dWhh + (size_t)grow*HIDDEN + c);
  }
  if (r < NTOK){
    #pragma unroll
    for (int k=0;k<8;++k) wout[k] = ld4(outW + (size_t)r*HIDDEN + (p*8+k)*4);
  } else {
    #pragma unroll
    for (int k=0;k<8;++k) wout[k] = make_float4(0.f,0.f,0.f,0.f);
  }

  // px for encoder steps: x_t @ Wih.T + bih + bhh (R1-identical order)
  {
    const float bsum = ebih[grow] + ebhh[grow];
    for (int ss = p; ss < ENC_T; ss += 8){
      const float* x  = enc_emb + (size_t)data[ss]*HIDDEN;
      const float* Wr = eWih + (size_t)grow*HIDDEN;
      float a = bsum;
      for (int c4=0;c4<64;++c4){
        float4 wv = ld4(Wr + c4*4); float4 xv = ld4(x + c4*4);
        a = fmaf(wv.x,xv.x, fmaf(wv.y,xv.y, fmaf(wv.z,xv.z, fmaf(wv.w,xv.w, a))));
      }
      pxe_sh[ss][r] = a;
    }
  }
  // px for ALL 28 possible decoder tokens (R1-identical order)
  {
    const float bsum = dbih[grow] + dbhh[grow];
    for (int tk = p; tk < NTOK; tk += 8){
      const float* x  = dec_emb + (size_t)tk*HIDDEN;
      const float* Wr = dWih + (size_t)grow*HIDDEN;
      float a = bsum;
      for (int c4=0;c4<64;++c4){
        float4 wv = ld4(Wr + c4*4); float4 xv = ld4(x + c4*4);
        a = fmaf(wv.x,fmaxf(xv.x,0.f), fmaf(wv.y,fmaxf(xv.y,0.f),
            fmaf(wv.z,fmaxf(xv.z,0.f), fmaf(wv.w,fmaxf(xv.w,0.f), a))));
      }
      pxd_sh[tk][r] = a;
    }
  }

  const int dcnd = data_c[0];
  if (tid < 8)    tc_sh[tid]   = cond_emb[target_c[0]*8 + tid];
  if (tid < NTOK) outb_sh[tid] = outb[tid];
  h_sh[tid] = (tid >= HIDDEN-8) ? cond_emb[dcnd*8 + (tid-(HIDDEN-8))] : 0.f;
  if (tid < HPW){
    int idx = w*HPW + tid;
    c_sh[tid] = (idx >= HIDDEN-8) ? cond_emb[dcnd*8 + (idx-(HIDDEN-8))] : 0.f;
  }
  __syncthreads();

  int step = 1;
  // ---------------- encoder: 16 sequential steps ----------------
  for (int es=0; es<ENC_T; ++es, ++step){
    const float4* h4 = (const float4*)h_sh;
    float a = 0.f;
    #pragma unroll
    for (int k=0;k<8;++k){
      float4 hv = h4[p*8+k]; float4 wv = wenc[k];
      a = fmaf(wv.x,hv.x, fmaf(wv.y,hv.y, fmaf(wv.z,hv.z, fmaf(wv.w,hv.w, a))));
    }
    a += __shfl_xor(a,1); a += __shfl_xor(a,2); a += __shfl_xor(a,4);
    if (p==0) g_sh[r] = a + pxe_sh[es][r];
    __syncthreads();
    if (tid < HPW){
      float gi=g_sh[tid], gf=g_sh[8+tid], gg=g_sh[16+tid], go=g_sh[24+tid];
      float cc = sigf(gf)*c_sh[tid] + sigf(gi)*tanhf(gg);
      float hh = sigf(go)*tanhf(cc);
      c_sh[tid]=cc;
      astore(&hb[w*HPW + tid], ((u64)step<<32) | (u64)__float_as_uint(hh));
      if (es==ENC_T-1)
        astore(&cb[w*HPW + tid], ((u64)step<<32) | (u64)__float_as_uint(cc));
    }
    // tag-in-payload: each thread polls its own element, one IC round trip
    {
      u64 v;
      do { v = aload(&hb[tid]); } while ((unsigned)(v>>32) != (unsigned)step);
      h_sh[tid] = __uint_as_float((unsigned)v);
    }
    __syncthreads();
  }

  // ---------------- mid: mu's + fc1/fc2 (redundant per WG, R1-identical) ----------------
  {
    u64 v;
    do { v = aload(&cb[tid]); } while ((unsigned)(v>>32) != (unsigned)ENC_T);
    c2_sh[tid] = __uint_as_float((unsigned)v);
  }
  __syncthreads();
  {
    int row = tid>>2, q = tid&3;   // 64 rows (32 h_mu + 32 c_mu), 4 threads each
    const float* Wr = (row<32) ? (hmuW + (size_t)row*HIDDEN) : (cmuW + (size_t)(row-32)*HIDDEN);
    const float* v  = (row<32) ? h_sh : c2_sh;
    float a=0.f;
    for (int c4=q*16; c4<q*16+16; ++c4){
      float4 wv = ld4(Wr + c4*4);
      float4 vv = *(const float4*)(v + c4*4);
      a = fmaf(wv.x,vv.x, fmaf(wv.y,vv.y, fmaf(wv.z,vv.z, fmaf(wv.w,vv.w, a))));
    }
    a += __shfl_xor(a,1); a += __shfl_xor(a,2);
    if (q==0) mu_sh[row] = a + ((row<32)? hmub[row] : cmub[row-32]);
  }
  __syncthreads();
  {
    float a = fc1b[tid];
    const float* Wr = fc1W + (size_t)tid*40;
    #pragma unroll
    for (int k=0;k<32;++k) a = fmaf(Wr[k], mu_sh[k], a);
    #pragma unroll
    for (int k=0;k<8;++k)  a = fmaf(Wr[32+k], tc_sh[k], a);
    float a2 = 0.f;
    if (tid < HPW){
      int idx = w*HPW + tid;
      a2 = fc2b[idx];
      const float* W2 = fc2W + (size_t)idx*40;
      #pragma unroll
      for (int k=0;k<32;++k) a2 = fmaf(W2[k], mu_sh[32+k], a2);
      #pragma unroll
      for (int k=0;k<8;++k)  a2 = fmaf(W2[32+k], tc_sh[k], a2);
    }
    __syncthreads();
    h_sh[tid] = a;                 // decoder h0 (full, redundant in every WG)
    if (tid < HPW) c_sh[tid] = a2; // decoder c0 (own slice only)
    __syncthreads();
  }

  // ---------------- decoder: 25 sequential steps ----------------
  int tok = 0; // SOS
  for (int dt=0; dt<DECLEN; ++dt, ++step){
    const float4* h4 = (const float4*)h_sh;
    float a=0.f;
    #pragma unroll
    for (int k=0;k<8;++k){
      float4 hv = h4[p*8+k]; float4 wv = wdec[k];
      a = fmaf(wv.x,hv.x, fmaf(wv.y,hv.y, fmaf(wv.z,hv.z, fmaf(wv.w,hv.w, a))));
    }
    a += __shfl_xor(a,1); a += __shfl_xor(a,2); a += __shfl_xor(a,4);
    if (p==0) g_sh[r] = a + pxd_sh[tok][r];
    __syncthreads();
    if (tid < HPW){
      float gi=g_sh[tid], gf=g_sh[8+tid], gg=g_sh[16+tid], go=g_sh[24+tid];
      float cc = sigf(gf)*c_sh[tid] + sigf(gi)*tanhf(gg);
      float hh = sigf(go)*tanhf(cc);
      c_sh[tid]=cc;
      astore(&hb[w*HPW + tid], ((u64)step<<32) | (u64)__float_as_uint(hh));
    }
    {
      u64 v;
      do { v = aload(&hb[tid]); } while ((unsigned)(v>>32) != (unsigned)step);
      h_sh[tid] = __uint_as_float((unsigned)v);
    }
    __syncthreads();
    // logits + argmax, redundant in every WG (R1-identical order)
    {
      const float4* h4b = (const float4*)h_sh;
      if (r < NTOK){
        float la=0.f;
        #pragma unroll
        for (int k=0;k<8;++k){
          float4 hv = h4b[p*8+k]; float4 wv = wout[k];
          la = fmaf(wv.x,hv.x, fmaf(wv.y,hv.y, fmaf(wv.z,hv.z, fmaf(wv.w,hv.w, la))));
        }
        la += __shfl_xor(la,1); la += __shfl_xor(la,2); la += __shfl_xor(la,4);
        if (p==0) l_sh[r] = la + outb_sh[r];
      }
    }
    __syncthreads();
    if (tid==0){
      float best = l_sh[0]; int bi=0;
      #pragma unroll
      for (int i=1;i<NTOK;++i){ if (l_sh[i] > best){ best=l_sh[i]; bi=i; } }
      tok_sh = bi;
    }
    __syncthreads();
    tok = tok_sh;
    if (w==0){
      if (tid < NTOK) out[dt*NTOK + tid] = l_sh[tid];
      if (tid==0)     out[DECLEN*NTOK + dt] = (float)tok_sh;
    }
  }
}

extern "C" void kernel_launch(void* const* d_in, const int* in_sizes, int n_in,
                              void* d_out, int out_size, void* d_ws, size_t ws_size,
                              hipStream_t stream)
{
  u64* hb = (u64*)d_ws;                        // 256 tagged h slots (2 KB)
  u64* cb = (u64*)((char*)d_ws + 2048);        // 256 tagged c slots (2 KB)
  hipMemsetAsync(d_ws, 0, 4096, stream);       // clear tags every launch

  vae_lstm_kernel<<<NWG, NTHR, 0, stream>>>(
    (const int*)d_in[0], (const int*)d_in[1], (const int*)d_in[2],
    (const float*)d_in[3], (const float*)d_in[4],
    (const float*)d_in[5], (const float*)d_in[6], (const float*)d_in[7], (const float*)d_in[8],
    (const float*)d_in[9], (const float*)d_in[10], (const float*)d_in[11], (const float*)d_in[12],
    (const float*)d_in[13], (const float*)d_in[14], (const float*)d_in[15], (const float*)d_in[16],
    (const float*)d_in[17], (const float*)d_in[18], (const float*)d_in[19], (const float*)d_in[20],
    (const float*)d_in[21], (const float*)d_in[22], (const float*)d_in[23],
    (float*)d_out, hb, cb);
}